// Round 10
// baseline (392.948 us; speedup 1.0000x reference)
//
#include <hip/hip_runtime.h>
#include <math.h>

#define KNN 16
#define NPTS 8192
#define PTCH 256
#define NPATCH 32
#define NBATCH 4

// spatial hash grid
#define H 0.35f
#define INVH 2.857142857f
#define ORG -4.55f
#define DIM 26
#define NCELL (DIM * DIM * DIM)
#define CAP 48
#define CNT_BYTES ((size_t)NBATCH * NCELL * 4)
#define SLOT_BYTES ((size_t)NBATCH * NCELL * CAP * 2)

// E[#points within distance s of a query at radius r], N iid N(0,I3). fp32.
// Heuristic only: exactness guaranteed by margin check + exact fallback.
__device__ __forceinline__ float lam_f(float r, float s)
{
    const float C     = 0.063493636f;    // (2*pi)^{-3/2}
    const float SQ2PI = 2.5066283f;
    const float IS2   = 0.70710678f;
    float a = fabsf(r - s), b = r + s;
    float amr = a - r;
    float coefA = amr * amr + 2.f - s * s;   // == 2 when r >= s
    float I = 2.f * __expf(-0.5f * b * b) - coefA * __expf(-0.5f * a * a)
            + r * SQ2PI * (erff(b * IS2) - erff(a * IS2));
    float M = C * (3.14159265f / r) * I;
    if (s > r) {
        float u = s - r;
        M += 12.566371f * C * (1.2533141f * erff(u * IS2) - u * __expf(-0.5f * u * u));
    }
    return (float)NPTS * M;
}

// ---------- fp32 cyclic Jacobi 3x3 (verified R9: absmax 0.0 vs bf16-rounded ref) ----
__device__ __forceinline__ void jrotf(float& app, float& aqq, float& apq,
                                      float& arp, float& arq,
                                      float& vp0, float& vq0,
                                      float& vp1, float& vq1,
                                      float& vp2, float& vq2)
{
    float g = apq;
    if (g == 0.f) return;
    float theta = (aqq - app) / (2.f * g);
    float at = fabsf(theta);
    float t = (at > 1.0e18f) ? (0.5f / theta)
                             : (copysignf(1.f, theta) / (at + sqrtf(theta * theta + 1.f)));
    float c = 1.f / sqrtf(t * t + 1.f);
    float s = t * c;
    float tau = s / (1.f + c);
    app -= t * g;
    aqq += t * g;
    apq = 0.f;
    float rp = arp, rq = arq;
    arp = rp - s * (rq + tau * rp);
    arq = rq + s * (rp - tau * rq);
    float p0 = vp0, q0 = vq0;
    vp0 = p0 - s * (q0 + tau * p0); vq0 = q0 + s * (p0 - tau * q0);
    float p1 = vp1, q1 = vq1;
    vp1 = p1 - s * (q1 + tau * p1); vq1 = q1 + s * (p1 - tau * q1);
    float p2 = vp2, q2 = vq2;
    vp2 = p2 - s * (q2 + tau * p2); vq2 = q2 + s * (p2 - tau * q2);
}

__device__ __forceinline__ void eig3f(float a00, float a11, float a22,
                                      float a01, float a02, float a12,
                                      float& nx, float& ny, float& nz,
                                      float& lmin, float& lsum)
{
    float v00 = 1, v01 = 0, v02 = 0;
    float v10 = 0, v11 = 1, v12 = 0;
    float v20 = 0, v21 = 0, v22 = 1;
    float scale = fabsf(a00) + fabsf(a11) + fabsf(a22) + fabsf(a01) + fabsf(a02) + fabsf(a12);
    if (scale > 0.f) {
        for (int sweep = 0; sweep < 6; ++sweep) {
            float off = fabsf(a01) + fabsf(a02) + fabsf(a12);
            if (off <= scale * 1e-7f) break;
            jrotf(a00, a11, a01, a02, a12, v00, v01, v10, v11, v20, v21);
            jrotf(a00, a22, a02, a01, a12, v00, v02, v10, v12, v20, v22);
            jrotf(a11, a22, a12, a01, a02, v01, v02, v11, v12, v21, v22);
        }
    }
    lsum = a00 + a11 + a22;
    lmin = a00; nx = v00; ny = v10; nz = v20;
    if (a11 < lmin) { lmin = a11; nx = v01; ny = v11; nz = v21; }
    if (a22 < lmin) { lmin = a22; nx = v02; ny = v12; nz = v22; }
}

// u32 key: (d2 float bits, low 13 mantissa bits cleared) | idx(13b). Ties -> lower idx.
__device__ __forceinline__ unsigned mkkey(float d2, unsigned idx) {
    return (__float_as_uint(d2) & 0xFFFFE000u) | idx;
}

// Caller guarantees key < L[15]. Sorted-ascending bubble (v_min/v_max pairs).
__device__ __forceinline__ void insert16(unsigned key, unsigned* L)
{
    L[KNN - 1] = key;
    #pragma unroll
    for (int m = KNN - 1; m >= 1; --m) {
        unsigned a = L[m - 1], b = L[m];
        L[m - 1] = min(a, b);
        L[m]     = max(a, b);
    }
}

// Snapshot-based butterfly merge across 16-lane groups (steps 1,2,4,8).
// After: all 16 lanes hold the group's merged top-16.
__device__ __forceinline__ void merge16(unsigned* L, int lane)
{
    #pragma unroll
    for (int step = 1; step <= 8; step <<= 1) {
        unsigned tmp[KNN];
        #pragma unroll
        for (int m = 0; m < KNN; ++m) tmp[m] = __shfl(L[m], lane ^ step, 64);
        for (int m = 0; m < KNN; ++m) {
            if (tmp[m] >= L[KNN - 1]) break;
            insert16(tmp[m], L);
        }
    }
}

// ---------------- binning kernel: 32768 threads, capacity bins -----------------
__global__ void bin_kernel(const float* __restrict__ pts, unsigned* __restrict__ cnts,
                           unsigned short* __restrict__ slots, float* __restrict__ out)
{
    int i = blockIdx.x * 256 + threadIdx.x;   // 0 .. 32767
    if (i == 0) { out[0] = 0.f; out[1] = 0.f; }
    int b = i >> 13, pi = i & (NPTS - 1);
    const float* p = pts + ((size_t)b * NPTS + pi) * 3;
    float x = p[0], y = p[1], z = p[2];
    int ix = min(max((int)floorf((x - ORG) * INVH), 0), DIM - 1);
    int iy = min(max((int)floorf((y - ORG) * INVH), 0), DIM - 1);
    int iz = min(max((int)floorf((z - ORG) * INVH), 0), DIM - 1);
    unsigned cell = (unsigned)(ix + DIM * (iy + DIM * iz));
    unsigned* cb = cnts + (size_t)b * NCELL;
    unsigned j = atomicAdd(&cb[cell], 1u);
    if (j < CAP) slots[((size_t)b * NCELL + cell) * CAP + j] = (unsigned short)pi;
}

// ---------------- main kernel: 16 queries/block, 16 lanes/query ----------------
__global__ void __launch_bounds__(256, 8)
spl_bin(const float* __restrict__ pts, const unsigned* __restrict__ cnts,
        const unsigned short* __restrict__ slots, float* __restrict__ out)
{
    __shared__ float4 pbuf4[PTCH];   // own patch, padded
    __shared__ double rb[8];

    const int t = threadIdx.x;
    const int w = t >> 6;
    const int lane = t & 63;
    const int g = t >> 4;            // query group 0..15
    const int l = t & 15;            // lane within group
    const unsigned gbase = (unsigned)(lane & 48);  // group's bit base in wave ballots
    const int p = blockIdx.x;
    const int six = blockIdx.y;
    const int b = blockIdx.z;

    const float* base = pts + (size_t)b * (NPTS * 3);
    const unsigned* cb = cnts + (size_t)b * NCELL;
    const unsigned short* sb = slots + (size_t)b * NCELL * CAP;

    // Stage own patch into padded LDS.
    {
        const float* src = base + p * (PTCH * 3);
        float* dst = (float*)pbuf4;
        #pragma unroll
        for (int s = 0; s < 3; ++s) {
            int f = t + s * 256;
            int j = f / 3;
            int c = f - 3 * j;
            dst[j * 4 + c] = src[f];
        }
    }
    __syncthreads();

    float4 qv = pbuf4[six * 16 + g];
    const float qx = qv.x, qy = qv.y, qz = qv.z;
    const float r = fmaxf(sqrtf(qx * qx + qy * qy + qz * qz), 1e-3f);

    // ---- lane-parallel gate ladder: 16 radii at once, 2 rounds (+1 patch) ----
    const float STEP = 0.2f, STEP2 = 0.0125f;
    float lam1 = lam_f(r, STEP * (float)(l + 1));
    unsigned long long balG = __ballot(lam1 < 64.f);     // global target: 64 of 8192
    unsigned long long balP = __ballot(lam1 < 1280.f);   // patch target: 40 of 256
    unsigned cG = __popc((unsigned)((balG >> gbase) & 0xFFFFu));
    unsigned cP = __popc((unsigned)((balP >> gbase) & 0xFFFFu));
    float loG = STEP * (float)cG;
    float loP = STEP * (float)cP;
    unsigned long long bal2 = __ballot(lam_f(r, loG + STEP2 * (float)(l + 1)) < 64.f);
    unsigned cG2 = __popc((unsigned)((bal2 >> gbase) & 0xFFFFu));
    float sG = loG + STEP2 * (float)(cG2 + 1);
    float gG = sG * sG;
    unsigned long long bal3 = __ballot(lam_f(r, loP + STEP2 * (float)(l + 1)) < 1280.f);
    unsigned cP2 = __popc((unsigned)((bal3 >> gbase) & 0xFFFFu));
    float sP = loP + STEP2 * (float)(cP2 + 1);
    float gP = sP * sP;

    // ---- global kNN: scan cells overlapping ball(q, sG) ----
    unsigned gl[KNN];
    #pragma unroll
    for (int m = 0; m < KNN; ++m) gl[m] = 0xFFFFFFFFu;
    int myCnt = 0;
    bool over = false;
    {
        int ilx = min(max((int)floorf((qx - sG - ORG) * INVH - 1e-4f), 0), DIM - 1);
        int ihx = min(max((int)floorf((qx + sG - ORG) * INVH + 1e-4f), 0), DIM - 1);
        int ily = min(max((int)floorf((qy - sG - ORG) * INVH - 1e-4f), 0), DIM - 1);
        int ihy = min(max((int)floorf((qy + sG - ORG) * INVH + 1e-4f), 0), DIM - 1);
        int ilz = min(max((int)floorf((qz - sG - ORG) * INVH - 1e-4f), 0), DIM - 1);
        int ihz = min(max((int)floorf((qz + sG - ORG) * INVH + 1e-4f), 0), DIM - 1);
        int nx = ihx - ilx + 1, ny = ihy - ily + 1, nz = ihz - ilz + 1;
        int ncell = nx * ny * nz;
        #pragma unroll 1
        for (int c = l; c < ncell; c += 16) {
            int cx = c % nx;
            int rest = c / nx;
            int cy = rest % ny;
            int cz = rest / ny;
            unsigned cell = (unsigned)((ilx + cx) + DIM * ((ily + cy) + DIM * (ilz + cz)));
            unsigned cnt = cb[cell];
            over |= (cnt > CAP);
            cnt = min(cnt, (unsigned)CAP);
            #pragma unroll 1
            for (unsigned j = 0; j < cnt; ++j) {
                unsigned idx = sb[cell * CAP + j];
                float cx_ = base[idx * 3 + 0];
                float cy_ = base[idx * 3 + 1];
                float cz_ = base[idx * 3 + 2];
                float dx = qx - cx_, dy = qy - cy_, dz = qz - cz_;
                float d2 = dx * dx + dy * dy + dz * dz;   // reference-form d2
                if (d2 < gG) {
                    ++myCnt;
                    unsigned k = mkkey(d2, idx);
                    if (k < gl[KNN - 1]) insert16(k, gl);
                }
            }
        }
    }
    #pragma unroll
    for (int s = 1; s <= 8; s <<= 1) myCnt += __shfl_xor(myCnt, s);
    unsigned long long ob = __ballot(over);
    bool overG = ((ob >> gbase) & 0xFFFFu) != 0ull;
    merge16(gl, lane);
    bool valid = (myCnt >= KNN) && !overG;
    if (valid) {
        float upper = __uint_as_float((gl[KNN - 1] & 0xFFFFE000u) + 0x2000u);
        valid = (upper < gG * 0.999f - 1e-5f);
    }
    if (!valid) {   // exact fallback: 16-lane full scan + merge (P ~ 1e-6/query)
        #pragma unroll
        for (int m = 0; m < KNN; ++m) gl[m] = 0xFFFFFFFFu;
        #pragma unroll 1
        for (int i = l; i < NPTS; i += 16) {
            float dx = qx - base[i * 3 + 0];
            float dy = qy - base[i * 3 + 1];
            float dz = qz - base[i * 3 + 2];
            float d2 = dx * dx + dy * dy + dz * dz;
            unsigned k = mkkey(d2, (unsigned)i);
            if (k < gl[KNN - 1]) insert16(k, gl);
        }
        merge16(gl, lane);
    }

    // ---- patch kNN: 256 pts, analytic patch gate, 16 lanes ----
    unsigned pl[KNN];
    #pragma unroll
    for (int m = 0; m < KNN; ++m) pl[m] = 0xFFFFFFFFu;
    int pCnt = 0;
    #pragma unroll 1
    for (int j = l; j < PTCH; j += 16) {
        float4 c = pbuf4[j];
        float dx = qx - c.x, dy = qy - c.y, dz = qz - c.z;
        float d2 = dx * dx + dy * dy + dz * dz;
        if (d2 < gP) {
            ++pCnt;
            unsigned k = mkkey(d2, (unsigned)j);
            if (k < pl[KNN - 1]) insert16(k, pl);
        }
    }
    #pragma unroll
    for (int s = 1; s <= 8; s <<= 1) pCnt += __shfl_xor(pCnt, s);
    merge16(pl, lane);
    bool validP = (pCnt >= KNN);
    if (validP) {
        float upperP = __uint_as_float((pl[KNN - 1] & 0xFFFFE000u) + 0x2000u);
        validP = (upperP < gP * 0.999f - 1e-5f);
    }
    if (!validP) {   // exact fallback: ungated 256-pt scan
        #pragma unroll
        for (int m = 0; m < KNN; ++m) pl[m] = 0xFFFFFFFFu;
        #pragma unroll 1
        for (int j = l; j < PTCH; j += 16) {
            float4 c = pbuf4[j];
            float dx = qx - c.x, dy = qy - c.y, dz = qz - c.z;
            float d2 = dx * dx + dy * dy + dz * dz;
            unsigned k = mkkey(d2, (unsigned)j);
            if (k < pl[KNN - 1]) insert16(k, pl);
        }
        merge16(pl, lane);
    }

    // ---- eigensolves + loss on group-lead lanes ----
    double ln = 0.0, lsv = 0.0;
    if (l == 0) {
        float c00 = 0, c11 = 0, c22 = 0, c01 = 0, c02 = 0, c12 = 0;
        #pragma unroll
        for (int m = 0; m < KNN; ++m) {
            int idx = (int)(gl[m] & 0x1FFFu);
            float dx = base[idx * 3 + 0] - qx;
            float dy = base[idx * 3 + 1] - qy;
            float dz = base[idx * 3 + 2] - qz;
            c00 += dx * dx; c11 += dy * dy; c22 += dz * dz;
            c01 += dx * dy; c02 += dx * dz; c12 += dy * dz;
        }
        float ngx, ngy, ngz, lminG, lsumG;
        eig3f(c00, c11, c22, c01, c02, c12, ngx, ngy, ngz, lminG, lsumG);
        float svg = lminG / lsumG;

        float p00 = 0, p11 = 0, p22 = 0, p01 = 0, p02 = 0, p12 = 0;
        #pragma unroll
        for (int m = 0; m < KNN; ++m) {
            int idx = (int)(pl[m] & 0xFFu);
            float4 cpt = pbuf4[idx];
            float dx = cpt.x - qx;
            float dy = cpt.y - qy;
            float dz = cpt.z - qz;
            p00 += dx * dx; p11 += dy * dy; p22 += dz * dz;
            p01 += dx * dy; p02 += dx * dz; p12 += dy * dz;
        }
        float npx, npy, npz, lminP, lsumP;
        eig3f(p00, p11, p22, p01, p02, p12, npx, npy, npz, lminP, lsumP);
        float svp = lminP / lsumP;

        double dx = fabs((double)npx) - fabs((double)ngx);
        double dy = fabs((double)npy) - fabs((double)ngy);
        double dz = fabs((double)npz) - fabs((double)ngz);
        ln  = sqrt(dx * dx + dy * dy + dz * dz);
        double ds = (double)svp - (double)svg;
        lsv = ds * ds;
    }
    #pragma unroll
    for (int o = 32; o > 0; o >>= 1) {
        ln  += __shfl_down(ln, o);
        lsv += __shfl_down(lsv, o);
    }
    if (lane == 0) { rb[w * 2 + 0] = ln; rb[w * 2 + 1] = lsv; }
    __syncthreads();
    if (t == 0) {
        const double inv = 1.0 / (double)(NBATCH * NPTS);
        atomicAdd(&out[0], (float)((rb[0] + rb[2] + rb[4] + rb[6]) * inv));
        atomicAdd(&out[1], (float)((rb[1] + rb[3] + rb[5] + rb[7]) * inv));
    }
}

// ---------------- emergency exact kernel (only if ws too small) ----------------
__global__ void __launch_bounds__(256)
spl_exact(const float* __restrict__ pts, float* __restrict__ out)
{
    __shared__ double rb[2 * 4];
    int i = blockIdx.x * 256 + threadIdx.x;   // query 0..32767
    int b = i >> 13, qi = i & (NPTS - 1);
    const float* base = pts + (size_t)b * (NPTS * 3);
    float qx = base[qi * 3], qy = base[qi * 3 + 1], qz = base[qi * 3 + 2];

    unsigned gl[KNN], pl[KNN];
    #pragma unroll
    for (int m = 0; m < KNN; ++m) { gl[m] = 0xFFFFFFFFu; pl[m] = 0xFFFFFFFFu; }
    for (int j = 0; j < NPTS; ++j) {
        float dx = qx - base[j * 3], dy = qy - base[j * 3 + 1], dz = qz - base[j * 3 + 2];
        unsigned k = mkkey(dx * dx + dy * dy + dz * dz, (unsigned)j);
        if (k < gl[KNN - 1]) insert16(k, gl);
    }
    int p0 = (qi / PTCH) * PTCH;
    for (int j = 0; j < PTCH; ++j) {
        int jj = p0 + j;
        float dx = qx - base[jj * 3], dy = qy - base[jj * 3 + 1], dz = qz - base[jj * 3 + 2];
        unsigned k = mkkey(dx * dx + dy * dy + dz * dz, (unsigned)j);
        if (k < pl[KNN - 1]) insert16(k, pl);
    }
    float c00=0,c11=0,c22=0,c01=0,c02=0,c12=0, d00=0,d11=0,d22=0,d01=0,d02=0,d12=0;
    #pragma unroll
    for (int m = 0; m < KNN; ++m) {
        int idx = (int)(gl[m] & 0x1FFFu);
        float dx = base[idx*3]-qx, dy = base[idx*3+1]-qy, dz = base[idx*3+2]-qz;
        c00+=dx*dx; c11+=dy*dy; c22+=dz*dz; c01+=dx*dy; c02+=dx*dz; c12+=dy*dz;
        int jdx = p0 + (int)(pl[m] & 0xFFu);
        float ex = base[jdx*3]-qx, ey = base[jdx*3+1]-qy, ez = base[jdx*3+2]-qz;
        d00+=ex*ex; d11+=ey*ey; d22+=ez*ez; d01+=ex*ey; d02+=ex*ez; d12+=ey*ez;
    }
    float ngx,ngy,ngz,lmg,lsg, npx,npy,npz,lmp,lsp;
    eig3f(c00,c11,c22,c01,c02,c12, ngx,ngy,ngz,lmg,lsg);
    eig3f(d00,d11,d22,d01,d02,d12, npx,npy,npz,lmp,lsp);
    double dx = fabs((double)npx)-fabs((double)ngx);
    double dy = fabs((double)npy)-fabs((double)ngy);
    double dz = fabs((double)npz)-fabs((double)ngz);
    double ln = sqrt(dx*dx+dy*dy+dz*dz);
    double ds = (double)(lmp/lsp) - (double)(lmg/lsg);
    double lsv = ds*ds;
    #pragma unroll
    for (int o = 32; o > 0; o >>= 1) { ln += __shfl_down(ln,o); lsv += __shfl_down(lsv,o); }
    int w = threadIdx.x >> 6;
    if ((threadIdx.x & 63) == 0) { rb[w*2] = ln; rb[w*2+1] = lsv; }
    __syncthreads();
    if (threadIdx.x == 0) {
        const double inv = 1.0 / (double)(NBATCH * NPTS);
        atomicAdd(&out[0], (float)((rb[0]+rb[2]+rb[4]+rb[6]) * inv));
        atomicAdd(&out[1], (float)((rb[1]+rb[3]+rb[5]+rb[7]) * inv));
    }
}

extern "C" void kernel_launch(void* const* d_in, const int* in_sizes, int n_in,
                              void* d_out, int out_size, void* d_ws, size_t ws_size,
                              hipStream_t stream)
{
    const float* pts = (const float*)d_in[0];
    float* out = (float*)d_out;
    if (ws_size >= CNT_BYTES + SLOT_BYTES) {
        unsigned* cnts = (unsigned*)d_ws;
        unsigned short* slots = (unsigned short*)((char*)d_ws + CNT_BYTES);
        hipMemsetAsync(cnts, 0, CNT_BYTES, stream);
        hipLaunchKernelGGL(bin_kernel, dim3(NBATCH * NPTS / 256), dim3(256), 0, stream,
                           pts, cnts, slots, out);
        dim3 grid(NPATCH, 16, NBATCH);
        hipLaunchKernelGGL(spl_bin, grid, dim3(256), 0, stream, pts, cnts, slots, out);
    } else {
        hipMemsetAsync(out, 0, 2 * sizeof(float), stream);
        hipLaunchKernelGGL(spl_exact, dim3(NBATCH * NPTS / 256), dim3(256), 0, stream,
                           pts, out);
    }
}

// Round 11
// 332.526 us; speedup vs baseline: 1.1817x; 1.1817x over previous
//
#include <hip/hip_runtime.h>
#include <math.h>

#define KNN 16
#define NPTS 8192
#define PTCH 256
#define NPATCH 32
#define NBATCH 4

// spatial hash grid
#define H 0.35f
#define INVH 2.857142857f
#define ORG -4.55f
#define DIM 26
#define NCELL (DIM * DIM * DIM)
#define CAP 48
#define CNT_BYTES ((size_t)NBATCH * NCELL * 4)
#define SLOT_BYTES ((size_t)NBATCH * NCELL * CAP * 2)

// E[#points within distance s of a query at radius r], N iid N(0,I3). fp32.
// Heuristic only: exactness guaranteed by margin check + exact fallback.
__device__ __forceinline__ float lam_f(float r, float s)
{
    const float C     = 0.063493636f;    // (2*pi)^{-3/2}
    const float SQ2PI = 2.5066283f;
    const float IS2   = 0.70710678f;
    float a = fabsf(r - s), b = r + s;
    float amr = a - r;
    float coefA = amr * amr + 2.f - s * s;   // == 2 when r >= s
    float I = 2.f * __expf(-0.5f * b * b) - coefA * __expf(-0.5f * a * a)
            + r * SQ2PI * (erff(b * IS2) - erff(a * IS2));
    float M = C * (3.14159265f / r) * I;
    if (s > r) {
        float u = s - r;
        M += 12.566371f * C * (1.2533141f * erff(u * IS2) - u * __expf(-0.5f * u * u));
    }
    return (float)NPTS * M;
}

// ---------- fp32 cyclic Jacobi 3x3 (verified R9/R10: absmax 0.0) ----------
__device__ __forceinline__ void jrotf(float& app, float& aqq, float& apq,
                                      float& arp, float& arq,
                                      float& vp0, float& vq0,
                                      float& vp1, float& vq1,
                                      float& vp2, float& vq2)
{
    float g = apq;
    if (g == 0.f) return;
    float theta = (aqq - app) / (2.f * g);
    float at = fabsf(theta);
    float t = (at > 1.0e18f) ? (0.5f / theta)
                             : (copysignf(1.f, theta) / (at + sqrtf(theta * theta + 1.f)));
    float c = 1.f / sqrtf(t * t + 1.f);
    float s = t * c;
    float tau = s / (1.f + c);
    app -= t * g;
    aqq += t * g;
    apq = 0.f;
    float rp = arp, rq = arq;
    arp = rp - s * (rq + tau * rp);
    arq = rq + s * (rp - tau * rq);
    float p0 = vp0, q0 = vq0;
    vp0 = p0 - s * (q0 + tau * p0); vq0 = q0 + s * (p0 - tau * q0);
    float p1 = vp1, q1 = vq1;
    vp1 = p1 - s * (q1 + tau * p1); vq1 = q1 + s * (p1 - tau * q1);
    float p2 = vp2, q2 = vq2;
    vp2 = p2 - s * (q2 + tau * p2); vq2 = q2 + s * (p2 - tau * q2);
}

__device__ __forceinline__ void eig3f(float a00, float a11, float a22,
                                      float a01, float a02, float a12,
                                      float& nx, float& ny, float& nz,
                                      float& lmin, float& lsum)
{
    float v00 = 1, v01 = 0, v02 = 0;
    float v10 = 0, v11 = 1, v12 = 0;
    float v20 = 0, v21 = 0, v22 = 1;
    float scale = fabsf(a00) + fabsf(a11) + fabsf(a22) + fabsf(a01) + fabsf(a02) + fabsf(a12);
    if (scale > 0.f) {
        for (int sweep = 0; sweep < 6; ++sweep) {
            float off = fabsf(a01) + fabsf(a02) + fabsf(a12);
            if (off <= scale * 1e-7f) break;
            jrotf(a00, a11, a01, a02, a12, v00, v01, v10, v11, v20, v21);
            jrotf(a00, a22, a02, a01, a12, v00, v02, v10, v12, v20, v22);
            jrotf(a11, a22, a12, a01, a02, v01, v02, v11, v12, v21, v22);
        }
    }
    lsum = a00 + a11 + a22;
    lmin = a00; nx = v00; ny = v10; nz = v20;
    if (a11 < lmin) { lmin = a11; nx = v01; ny = v11; nz = v21; }
    if (a22 < lmin) { lmin = a22; nx = v02; ny = v12; nz = v22; }
}

// u32 key: (d2 float bits, low 13 mantissa bits cleared) | idx(13b). Ties -> lower idx.
__device__ __forceinline__ unsigned mkkey(float d2, unsigned idx) {
    return (__float_as_uint(d2) & 0xFFFFE000u) | idx;
}

// Caller guarantees key < L[15]. Sorted-ascending bubble (v_min/v_max pairs).
__device__ __forceinline__ void insert16(unsigned key, unsigned* L)
{
    L[KNN - 1] = key;
    #pragma unroll
    for (int m = KNN - 1; m >= 1; --m) {
        unsigned a = L[m - 1], b = L[m];
        L[m - 1] = min(a, b);
        L[m]     = max(a, b);
    }
}

// Snapshot-based butterfly merge across 16-lane groups (steps 1,2,4,8).
// FULLY UNROLLED (guard instead of break) so tmp[] stays in registers.
__device__ __forceinline__ void merge16(unsigned* L, int lane)
{
    #pragma unroll
    for (int step = 1; step <= 8; step <<= 1) {
        unsigned tmp[KNN];
        #pragma unroll
        for (int m = 0; m < KNN; ++m) tmp[m] = __shfl(L[m], lane ^ step, 64);
        #pragma unroll
        for (int m = 0; m < KNN; ++m) {
            if (tmp[m] < L[KNN - 1]) insert16(tmp[m], L);
        }
    }
}

// ---------------- binning kernel: 32768 threads, capacity bins -----------------
__global__ void bin_kernel(const float* __restrict__ pts, unsigned* __restrict__ cnts,
                           unsigned short* __restrict__ slots, float* __restrict__ out)
{
    int i = blockIdx.x * 256 + threadIdx.x;   // 0 .. 32767
    if (i == 0) { out[0] = 0.f; out[1] = 0.f; }
    int b = i >> 13, pi = i & (NPTS - 1);
    const float* p = pts + ((size_t)b * NPTS + pi) * 3;
    float x = p[0], y = p[1], z = p[2];
    int ix = min(max((int)floorf((x - ORG) * INVH), 0), DIM - 1);
    int iy = min(max((int)floorf((y - ORG) * INVH), 0), DIM - 1);
    int iz = min(max((int)floorf((z - ORG) * INVH), 0), DIM - 1);
    unsigned cell = (unsigned)(ix + DIM * (iy + DIM * iz));
    unsigned* cb = cnts + (size_t)b * NCELL;
    unsigned j = atomicAdd(&cb[cell], 1u);
    if (j < CAP) slots[((size_t)b * NCELL + cell) * CAP + j] = (unsigned short)pi;
}

// ---------------- main kernel: 16 queries/block, 16 lanes/query ----------------
__global__ void __launch_bounds__(256, 4)
spl_bin(const float* __restrict__ pts, const unsigned* __restrict__ cnts,
        const unsigned short* __restrict__ slots, float* __restrict__ out)
{
    __shared__ float4 pbuf4[PTCH];   // own patch, padded
    __shared__ double rb[8];

    const int t = threadIdx.x;
    const int w = t >> 6;
    const int lane = t & 63;
    const int g = t >> 4;            // query group 0..15
    const int l = t & 15;            // lane within group
    const unsigned gbase = (unsigned)(lane & 48);  // group's bit base in wave ballots
    const int p = blockIdx.x;
    const int six = blockIdx.y;
    const int b = blockIdx.z;

    const float* base = pts + (size_t)b * (NPTS * 3);
    const unsigned* cb = cnts + (size_t)b * NCELL;
    const unsigned short* sb = slots + (size_t)b * NCELL * CAP;

    // Stage own patch into padded LDS.
    {
        const float* src = base + p * (PTCH * 3);
        float* dst = (float*)pbuf4;
        #pragma unroll
        for (int s = 0; s < 3; ++s) {
            int f = t + s * 256;
            int j = f / 3;
            int c = f - 3 * j;
            dst[j * 4 + c] = src[f];
        }
    }
    __syncthreads();

    float4 qv = pbuf4[six * 16 + g];
    const float qx = qv.x, qy = qv.y, qz = qv.z;
    const float r = fmaxf(sqrtf(qx * qx + qy * qy + qz * qz), 1e-3f);

    // ---- lane-parallel gate ladder: 16 radii at once, 2 rounds (+1 patch) ----
    const float STEP = 0.2f, STEP2 = 0.0125f;
    float lam1 = lam_f(r, STEP * (float)(l + 1));
    unsigned long long balG = __ballot(lam1 < 64.f);     // global target: 64 of 8192
    unsigned long long balP = __ballot(lam1 < 1280.f);   // patch target: 40 of 256
    unsigned cG = __popc((unsigned)((balG >> gbase) & 0xFFFFu));
    unsigned cP = __popc((unsigned)((balP >> gbase) & 0xFFFFu));
    float loG = STEP * (float)cG;
    float loP = STEP * (float)cP;
    unsigned long long bal2 = __ballot(lam_f(r, loG + STEP2 * (float)(l + 1)) < 64.f);
    unsigned cG2 = __popc((unsigned)((bal2 >> gbase) & 0xFFFFu));
    float sG = loG + STEP2 * (float)(cG2 + 1);
    float gG = sG * sG;
    unsigned long long bal3 = __ballot(lam_f(r, loP + STEP2 * (float)(l + 1)) < 1280.f);
    unsigned cP2 = __popc((unsigned)((bal3 >> gbase) & 0xFFFFu));
    float sP = loP + STEP2 * (float)(cP2 + 1);
    float gP = sP * sP;

    // ---- global kNN: scan cells overlapping ball(q, sG) ----
    unsigned gl[KNN];
    #pragma unroll
    for (int m = 0; m < KNN; ++m) gl[m] = 0xFFFFFFFFu;
    int myCnt = 0;
    bool over = false;
    {
        int ilx = min(max((int)floorf((qx - sG - ORG) * INVH - 1e-4f), 0), DIM - 1);
        int ihx = min(max((int)floorf((qx + sG - ORG) * INVH + 1e-4f), 0), DIM - 1);
        int ily = min(max((int)floorf((qy - sG - ORG) * INVH - 1e-4f), 0), DIM - 1);
        int ihy = min(max((int)floorf((qy + sG - ORG) * INVH + 1e-4f), 0), DIM - 1);
        int ilz = min(max((int)floorf((qz - sG - ORG) * INVH - 1e-4f), 0), DIM - 1);
        int ihz = min(max((int)floorf((qz + sG - ORG) * INVH + 1e-4f), 0), DIM - 1);
        int nx = ihx - ilx + 1, ny = ihy - ily + 1, nz = ihz - ilz + 1;
        int ncell = nx * ny * nz;
        #pragma unroll 1
        for (int c = l; c < ncell; c += 16) {
            int cx = c % nx;
            int rest = c / nx;
            int cy = rest % ny;
            int cz = rest / ny;
            unsigned cell = (unsigned)((ilx + cx) + DIM * ((ily + cy) + DIM * (ilz + cz)));
            unsigned cnt = cb[cell];
            over |= (cnt > CAP);
            cnt = min(cnt, (unsigned)CAP);
            const unsigned short* cs = sb + cell * CAP;
            #pragma unroll 2
            for (unsigned j = 0; j < cnt; ++j) {
                unsigned idx = cs[j];
                float cx_ = base[idx * 3 + 0];
                float cy_ = base[idx * 3 + 1];
                float cz_ = base[idx * 3 + 2];
                float dx = qx - cx_, dy = qy - cy_, dz = qz - cz_;
                float d2 = dx * dx + dy * dy + dz * dz;   // reference-form d2
                if (d2 < gG) {
                    ++myCnt;
                    unsigned k = mkkey(d2, idx);
                    if (k < gl[KNN - 1]) insert16(k, gl);
                }
            }
        }
    }
    #pragma unroll
    for (int s = 1; s <= 8; s <<= 1) myCnt += __shfl_xor(myCnt, s);
    unsigned long long ob = __ballot(over);
    bool overG = ((ob >> gbase) & 0xFFFFu) != 0ull;
    merge16(gl, lane);
    bool valid = (myCnt >= KNN) && !overG;
    if (valid) {
        float upper = __uint_as_float((gl[KNN - 1] & 0xFFFFE000u) + 0x2000u);
        valid = (upper < gG * 0.999f - 1e-5f);
    }
    if (!valid) {   // exact fallback: 16-lane full scan + merge (rare)
        #pragma unroll
        for (int m = 0; m < KNN; ++m) gl[m] = 0xFFFFFFFFu;
        #pragma unroll 1
        for (int i = l; i < NPTS; i += 16) {
            float dx = qx - base[i * 3 + 0];
            float dy = qy - base[i * 3 + 1];
            float dz = qz - base[i * 3 + 2];
            float d2 = dx * dx + dy * dy + dz * dz;
            unsigned k = mkkey(d2, (unsigned)i);
            if (k < gl[KNN - 1]) insert16(k, gl);
        }
        merge16(gl, lane);
    }

    // ---- patch kNN: 256 pts, analytic patch gate, 16 lanes ----
    unsigned pl[KNN];
    #pragma unroll
    for (int m = 0; m < KNN; ++m) pl[m] = 0xFFFFFFFFu;
    int pCnt = 0;
    #pragma unroll 1
    for (int j = l; j < PTCH; j += 16) {
        float4 c = pbuf4[j];
        float dx = qx - c.x, dy = qy - c.y, dz = qz - c.z;
        float d2 = dx * dx + dy * dy + dz * dz;
        if (d2 < gP) {
            ++pCnt;
            unsigned k = mkkey(d2, (unsigned)j);
            if (k < pl[KNN - 1]) insert16(k, pl);
        }
    }
    #pragma unroll
    for (int s = 1; s <= 8; s <<= 1) pCnt += __shfl_xor(pCnt, s);
    merge16(pl, lane);
    bool validP = (pCnt >= KNN);
    if (validP) {
        float upperP = __uint_as_float((pl[KNN - 1] & 0xFFFFE000u) + 0x2000u);
        validP = (upperP < gP * 0.999f - 1e-5f);
    }
    if (!validP) {   // exact fallback: ungated 256-pt scan
        #pragma unroll
        for (int m = 0; m < KNN; ++m) pl[m] = 0xFFFFFFFFu;
        #pragma unroll 1
        for (int j = l; j < PTCH; j += 16) {
            float4 c = pbuf4[j];
            float dx = qx - c.x, dy = qy - c.y, dz = qz - c.z;
            float d2 = dx * dx + dy * dy + dz * dz;
            unsigned k = mkkey(d2, (unsigned)j);
            if (k < pl[KNN - 1]) insert16(k, pl);
        }
        merge16(pl, lane);
    }

    // ---- unified eigensolve: lane0 = global list, lane1 = patch list ----
    float nx = 0.f, ny = 0.f, nz = 0.f, svv = 0.f;
    if (l < 2) {
        float c00 = 0, c11 = 0, c22 = 0, c01 = 0, c02 = 0, c12 = 0;
        #pragma unroll
        for (int m = 0; m < KNN; ++m) {
            unsigned key = (l == 0) ? gl[m] : pl[m];
            int idx = (l == 0) ? (int)(key & 0x1FFFu)
                               : (p * PTCH + (int)(key & 0xFFu));
            float dx = base[idx * 3 + 0] - qx;
            float dy = base[idx * 3 + 1] - qy;
            float dz = base[idx * 3 + 2] - qz;
            c00 += dx * dx; c11 += dy * dy; c22 += dz * dz;
            c01 += dx * dy; c02 += dx * dz; c12 += dy * dz;
        }
        float lmin, lsum;
        eig3f(c00, c11, c22, c01, c02, c12, nx, ny, nz, lmin, lsum);
        svv = lmin / lsum;
    }

    double ln = 0.0, lsv = 0.0;
    {
        // lane0 pulls lane1's (patch) results
        float npx = __shfl(nx, lane + 1, 64);
        float npy = __shfl(ny, lane + 1, 64);
        float npz = __shfl(nz, lane + 1, 64);
        float svp = __shfl(svv, lane + 1, 64);
        if (l == 0) {
            double dx = fabs((double)npx) - fabs((double)nx);
            double dy = fabs((double)npy) - fabs((double)ny);
            double dz = fabs((double)npz) - fabs((double)nz);
            ln  = sqrt(dx * dx + dy * dy + dz * dz);
            double ds = (double)svp - (double)svv;
            lsv = ds * ds;
        }
    }
    #pragma unroll
    for (int o = 32; o > 0; o >>= 1) {
        ln  += __shfl_down(ln, o);
        lsv += __shfl_down(lsv, o);
    }
    if (lane == 0) { rb[w * 2 + 0] = ln; rb[w * 2 + 1] = lsv; }
    __syncthreads();
    if (t == 0) {
        const double inv = 1.0 / (double)(NBATCH * NPTS);
        atomicAdd(&out[0], (float)((rb[0] + rb[2] + rb[4] + rb[6]) * inv));
        atomicAdd(&out[1], (float)((rb[1] + rb[3] + rb[5] + rb[7]) * inv));
    }
}

// ---------------- emergency exact kernel (only if ws too small) ----------------
__global__ void __launch_bounds__(256)
spl_exact(const float* __restrict__ pts, float* __restrict__ out)
{
    __shared__ double rb[2 * 4];
    int i = blockIdx.x * 256 + threadIdx.x;   // query 0..32767
    int b = i >> 13, qi = i & (NPTS - 1);
    const float* base = pts + (size_t)b * (NPTS * 3);
    float qx = base[qi * 3], qy = base[qi * 3 + 1], qz = base[qi * 3 + 2];

    unsigned gl[KNN], pl[KNN];
    #pragma unroll
    for (int m = 0; m < KNN; ++m) { gl[m] = 0xFFFFFFFFu; pl[m] = 0xFFFFFFFFu; }
    for (int j = 0; j < NPTS; ++j) {
        float dx = qx - base[j * 3], dy = qy - base[j * 3 + 1], dz = qz - base[j * 3 + 2];
        unsigned k = mkkey(dx * dx + dy * dy + dz * dz, (unsigned)j);
        if (k < gl[KNN - 1]) insert16(k, gl);
    }
    int p0 = (qi / PTCH) * PTCH;
    for (int j = 0; j < PTCH; ++j) {
        int jj = p0 + j;
        float dx = qx - base[jj * 3], dy = qy - base[jj * 3 + 1], dz = qz - base[jj * 3 + 2];
        unsigned k = mkkey(dx * dx + dy * dy + dz * dz, (unsigned)j);
        if (k < pl[KNN - 1]) insert16(k, pl);
    }
    float c00=0,c11=0,c22=0,c01=0,c02=0,c12=0, d00=0,d11=0,d22=0,d01=0,d02=0,d12=0;
    #pragma unroll
    for (int m = 0; m < KNN; ++m) {
        int idx = (int)(gl[m] & 0x1FFFu);
        float dx = base[idx*3]-qx, dy = base[idx*3+1]-qy, dz = base[idx*3+2]-qz;
        c00+=dx*dx; c11+=dy*dy; c22+=dz*dz; c01+=dx*dy; c02+=dx*dz; c12+=dy*dz;
        int jdx = p0 + (int)(pl[m] & 0xFFu);
        float ex = base[jdx*3]-qx, ey = base[jdx*3+1]-qy, ez = base[jdx*3+2]-qz;
        d00+=ex*ex; d11+=ey*ey; d22+=ez*ez; d01+=ex*ey; d02+=ex*ez; d12+=ey*ez;
    }
    float ngx,ngy,ngz,lmg,lsg, npx,npy,npz,lmp,lsp;
    eig3f(c00,c11,c22,c01,c02,c12, ngx,ngy,ngz,lmg,lsg);
    eig3f(d00,d11,d22,d01,d02,d12, npx,npy,npz,lmp,lsp);
    double dx = fabs((double)npx)-fabs((double)ngx);
    double dy = fabs((double)npy)-fabs((double)ngy);
    double dz = fabs((double)npz)-fabs((double)ngz);
    double ln = sqrt(dx*dx+dy*dy+dz*dz);
    double ds = (double)(lmp/lsp) - (double)(lmg/lsg);
    double lsv = ds*ds;
    #pragma unroll
    for (int o = 32; o > 0; o >>= 1) { ln += __shfl_down(ln,o); lsv += __shfl_down(lsv,o); }
    int w = threadIdx.x >> 6;
    if ((threadIdx.x & 63) == 0) { rb[w*2] = ln; rb[w*2+1] = lsv; }
    __syncthreads();
    if (threadIdx.x == 0) {
        const double inv = 1.0 / (double)(NBATCH * NPTS);
        atomicAdd(&out[0], (float)((rb[0]+rb[2]+rb[4]+rb[6]) * inv));
        atomicAdd(&out[1], (float)((rb[1]+rb[3]+rb[5]+rb[7]) * inv));
    }
}

extern "C" void kernel_launch(void* const* d_in, const int* in_sizes, int n_in,
                              void* d_out, int out_size, void* d_ws, size_t ws_size,
                              hipStream_t stream)
{
    const float* pts = (const float*)d_in[0];
    float* out = (float*)d_out;
    if (ws_size >= CNT_BYTES + SLOT_BYTES) {
        unsigned* cnts = (unsigned*)d_ws;
        unsigned short* slots = (unsigned short*)((char*)d_ws + CNT_BYTES);
        hipMemsetAsync(cnts, 0, CNT_BYTES, stream);
        hipLaunchKernelGGL(bin_kernel, dim3(NBATCH * NPTS / 256), dim3(256), 0, stream,
                           pts, cnts, slots, out);
        dim3 grid(NPATCH, 16, NBATCH);
        hipLaunchKernelGGL(spl_bin, grid, dim3(256), 0, stream, pts, cnts, slots, out);
    } else {
        hipMemsetAsync(out, 0, 2 * sizeof(float), stream);
        hipLaunchKernelGGL(spl_exact, dim3(NBATCH * NPTS / 256), dim3(256), 0, stream,
                           pts, out);
    }
}